// Round 8
// baseline (142.621 us; speedup 1.0000x reference)
//
#include <hip/hip_runtime.h>
#include <hip/hip_bf16.h>

// Chamfer distance, B=16, N=M=4096, D=3, fp32 — fully fused MFMA kernel.
//
// d2(s,t) = |s|^2+|t|^2-2 s.t via ONE K=16 bf16 mfma_f32_32x32x16 per 32x32
// tile with hi/lo bf16 splitting (slot layout verified absmax==0 R4..R7):
//   A: [xh yh zh xh yh zh xl yl | zl fh fl 1 1 0 0 0]           (query s)
//   B: [-2xh -2yh -2zh -2xl -2yl -2zl -2xh -2yh | -2zh 1 1 fh fl 0 0 0] (t)
// Grid: dir(2) x batch(16) x strip(16 of 256 rows) x colhalf(2 of 2048)
//     = 1024 blocks x 256 thr = 4 blocks/CU, 16 waves/CU.
// Final reduction fused via tickets (base 0xFFFFFFFF from the 0xFF memset):
//   pair level: 2 col-half blocks atomicMin their 256 partial row-mins into
//   pairmin[pair][...]; 2nd ticket arrival (old==0) reads merged mins,
//   block-reduces to pairsum[pair]. global level: 512 pair-winners ticket;
//   the one seeing old==510 sums the 512 pairsums and stores out[0].
// 2 dispatches total: memset(0xFF, 516KB) + kernel.

#define BATCH   16
#define NPTS    4096
#define CHUNKC  512
#define COLSPB  2048
#define NCHUNKS (COLSPB / CHUNKC)      // 4
#define NSTRIPS 16                     // 4096/256 rows per block
#define NPAIRS  (2 * BATCH * NSTRIPS)  // 512

typedef __attribute__((ext_vector_type(8)))  short short8;
typedef __attribute__((ext_vector_type(16))) float float16;

union U4S8 { uint4 u; short8 s; };

__device__ inline unsigned int bfb(float v) {
    __hip_bfloat16 h = __float2bfloat16(v);
    unsigned short u; __builtin_memcpy(&u, &h, 2);
    return (unsigned int)u;
}
__device__ inline float bff(float v) { return __bfloat162float(__float2bfloat16(v)); }

#define ONEB 0x3F80u

__device__ inline void buildA(float x, float y, float z, uint4& w0, uint4& w1) {
    float xhf = bff(x), yhf = bff(y), zhf = bff(z);
    float f = fmaf(x, x, fmaf(y, y, z * z));
    float fhf = bff(f);
    unsigned xh = bfb(xhf), yh = bfb(yhf), zh = bfb(zhf);
    unsigned xl = bfb(x - xhf), yl = bfb(y - yhf), zl = bfb(z - zhf);
    unsigned fh = bfb(fhf), fl = bfb(f - fhf);
    w0 = make_uint4(xh | (yh << 16), zh | (xh << 16),
                    yh | (zh << 16), xl | (yl << 16));
    w1 = make_uint4(zl | (fh << 16), fl | (ONEB << 16), ONEB, 0u);
}

__device__ inline void buildB(float x, float y, float z, uint4& w0, uint4& w1) {
    float xhf = bff(x), yhf = bff(y), zhf = bff(z);
    float f = fmaf(x, x, fmaf(y, y, z * z));
    float fhf = bff(f);
    unsigned a = bfb(-2.0f * xhf), b = bfb(-2.0f * yhf), c = bfb(-2.0f * zhf);
    unsigned d = bfb(-2.0f * (x - xhf)), e = bfb(-2.0f * (y - yhf)),
             g = bfb(-2.0f * (z - zhf));
    unsigned fh = bfb(fhf), fl = bfb(f - fhf);
    w0 = make_uint4(a | (b << 16), c | (d << 16),
                    e | (g << 16), a | (b << 16));
    w1 = make_uint4(c | (ONEB << 16), ONEB | (fh << 16), fl, 0u);
}

__global__ __launch_bounds__(256, 4) void chamfer_kernel(
    const float* __restrict__ src, const float* __restrict__ tgt,
    unsigned int* __restrict__ pairmin,   // [NPAIRS][256]
    unsigned int* __restrict__ ptick,     // [NPAIRS]
    unsigned int* __restrict__ gtick,     // [1]
    unsigned int* __restrict__ pairsum,   // [NPAIRS] (float bits)
    float* __restrict__ out)
{
    __shared__ uint4 sbuf[2][2][CHUNKC];    // [buf][half][pt] = 32 KB
    __shared__ float wsum[4];
    __shared__ int flag;

    int blk = blockIdx.x;
    const int ch    = blk & 1;             blk >>= 1;
    const int strip = blk & (NSTRIPS - 1); blk >>= 4;
    const int b     = blk & 15;            blk >>= 4;
    const int dir   = blk;
    const int pair  = ((dir * BATCH + b) * NSTRIPS) + strip;

    const int t    = threadIdx.x;
    const int lane = t & 63;
    const int w    = t >> 6;
    const int half = lane >> 5;
    const int l5   = lane & 31;

    const float* Araw = (dir ? tgt : src) + (size_t)b * NPTS * 3;  // queries
    const float* Braw = (dir ? src : tgt) + (size_t)b * NPTS * 3;  // targets
    const int colbase = ch * COLSPB;

    // Pipelined B staging: raw loads early (regs), convert+ds_write late.
    float nx[2][3];
    auto loadRaw = [&](int c) {
#pragma unroll
        for (int k = 0; k < 2; k++) {
            int p = colbase + c * CHUNKC + t + k * 256;
            nx[k][0] = Braw[3 * p + 0];
            nx[k][1] = Braw[3 * p + 1];
            nx[k][2] = Braw[3 * p + 2];
        }
    };
    auto convertWrite = [&](int bi) {
#pragma unroll
        for (int k = 0; k < 2; k++) {
            int lp = t + k * 256;
            uint4 w0, w1;
            buildB(nx[k][0], nx[k][1], nx[k][2], w0, w1);
            sbuf[bi][0][lp] = w0;
            sbuf[bi][1][lp] = w1;
        }
    };

    loadRaw(0);   // in flight while we build A

    // A fragments: 2 row-groups of 32 rows per wave, built once.
    short8 afr[2];
#pragma unroll
    for (int g = 0; g < 2; g++) {
        int row = strip * 256 + g * 128 + w * 32 + l5;
        uint4 w0, w1;
        buildA(Araw[3 * row], Araw[3 * row + 1], Araw[3 * row + 2], w0, w1);
        U4S8 tt; tt.u = half ? w1 : w0;
        afr[g] = tt.s;
    }

    const float16 z16 = {0.f,0.f,0.f,0.f,0.f,0.f,0.f,0.f,
                         0.f,0.f,0.f,0.f,0.f,0.f,0.f,0.f};
    float rm[2][16];
#pragma unroll
    for (int g = 0; g < 2; g++)
#pragma unroll
        for (int r = 0; r < 16; r++) rm[g][r] = 1e30f;

    convertWrite(0);
    for (int c = 0; c < NCHUNKS; c++) {
        if (c + 1 < NCHUNKS) loadRaw(c + 1);   // issue before barrier wait
        __syncthreads();                        // buf[c&1] written everywhere
        const int bi = c & 1;
#pragma unroll 2
        for (int j2 = 0; j2 < CHUNKC / 64; j2++) {     // 8 steps of 64 cols
            U4S8 t0, t1;
            t0.u = sbuf[bi][half][j2 * 64 + l5];
            t1.u = sbuf[bi][half][j2 * 64 + 32 + l5];
#pragma unroll
            for (int g = 0; g < 2; g++) {
                float16 a0 = __builtin_amdgcn_mfma_f32_32x32x16_bf16(afr[g], t0.s, z16, 0, 0, 0);
                float16 a1 = __builtin_amdgcn_mfma_f32_32x32x16_bf16(afr[g], t1.s, z16, 0, 0, 0);
#pragma unroll
                for (int r = 0; r < 16; r++)
                    rm[g][r] = fminf(fminf(a0[r], a1[r]), rm[g][r]);   // v_min3
            }
        }
        if (c + 1 < NCHUNKS) convertWrite((c + 1) & 1);   // vmcnt hidden above
    }

    // Col-fold within half (masks 1..16 over lane&31); lanes l5==0 hold the
    // partial mins for rows (r&3)+8*(r>>2)+4*half of each group.
#pragma unroll
    for (int mask = 1; mask <= 16; mask <<= 1)
#pragma unroll
        for (int g = 0; g < 2; g++)
#pragma unroll
            for (int r = 0; r < 16; r++)
                rm[g][r] = fminf(rm[g][r], __shfl_xor(rm[g][r], mask, 64));

    if (l5 == 0) {
        unsigned int* pm = pairmin + (size_t)pair * 256;
#pragma unroll
        for (int g = 0; g < 2; g++)
#pragma unroll
            for (int r = 0; r < 16; r++) {
                int idx = g * 128 + w * 32 + (r & 3) + 8 * (r >> 2) + 4 * half;
                float v = fmaxf(rm[g][r], 0.0f);
                atomicMin(&pm[idx], __float_as_uint(v));
            }
    }

    // ---- pair ticket: 2 arrivals; base 0xFFFFFFFF -> second sees old==0 ----
    __threadfence();
    if (t == 0) {
        unsigned int old = atomicAdd(&ptick[pair], 1u);
        flag = (old == 0u);
    }
    __syncthreads();
    if (!flag) return;

    // Pair-winner: coherent readback of merged mins (atomic identity read).
    {
        float s = __uint_as_float(atomicMin(&pairmin[(size_t)pair * 256 + t], 0xFFFFFFFFu));
#pragma unroll
        for (int off = 32; off > 0; off >>= 1) s += __shfl_down(s, off, 64);
        if ((t & 63) == 0) wsum[t >> 6] = s;
    }
    __syncthreads();
    if (t == 0) {
        float ps = wsum[0] + wsum[1] + wsum[2] + wsum[3];
        atomicExch(&pairsum[pair], __float_as_uint(ps));
        __threadfence();
        unsigned int old = atomicAdd(gtick, 1u);   // olds: 0xFFFFFFFF,0..510
        flag = (old == (unsigned int)(NPAIRS - 2));
    }
    __syncthreads();
    if (!flag) return;

    // Global winner: sum all 512 pairsums, write the scalar output.
    {
        float s = __uint_as_float(atomicMin(&pairsum[t], 0xFFFFFFFFu))
                + __uint_as_float(atomicMin(&pairsum[t + 256], 0xFFFFFFFFu));
#pragma unroll
        for (int off = 32; off > 0; off >>= 1) s += __shfl_down(s, off, 64);
        if ((t & 63) == 0) wsum[t >> 6] = s;
    }
    __syncthreads();
    if (t == 0)
        out[0] = (wsum[0] + wsum[1] + wsum[2] + wsum[3]) * (1.0f / (float)NPTS);
}

extern "C" void kernel_launch(void* const* d_in, const int* in_sizes, int n_in,
                              void* d_out, int out_size, void* d_ws, size_t ws_size,
                              hipStream_t stream)
{
    const float* src = (const float*)d_in[0];
    const float* tgt = (const float*)d_in[1];
    float* out = (float*)d_out;

    unsigned int* pairmin = (unsigned int*)d_ws;          // 512*256 u32
    unsigned int* ptick   = pairmin + NPAIRS * 256;       // 512
    unsigned int* gtick   = ptick + NPAIRS;               // 1
    unsigned int* pairsum = gtick + 1;                    // 512

    // One 0xFF memset covers: pairmin (+inf for uint-min of non-neg floats),
    // ptick/gtick (base 0xFFFFFFFF -> wraparound ticket compares), pairsum
    // (written via atomicExch before any read).
    hipMemsetAsync(pairmin, 0xFF,
                   (size_t)(NPAIRS * 256 + NPAIRS + 1 + NPAIRS) * sizeof(unsigned int),
                   stream);

    chamfer_kernel<<<2 * BATCH * NSTRIPS * 2, 256, 0, stream>>>(
        src, tgt, pairmin, ptick, gtick, pairsum, out);
}

// Round 9
// 81.458 us; speedup vs baseline: 1.7509x; 1.7509x over previous
//
#include <hip/hip_runtime.h>
#include <hip/hip_bf16.h>

// Chamfer distance, B=16, N=M=4096, D=3, fp32 — single fused MFMA kernel.
//
// d2(s,t) = |s|^2+|t|^2-2 s.t via ONE K=16 bf16 mfma_f32_32x32x16 per 32x32
// tile with hi/lo bf16 splitting (slot layout verified absmax==0 R4..R8):
//   A: [xh yh zh xh yh zh xl yl | zl fh fl 1 1 0 0 0]           (query s)
//   B: [-2xh -2yh -2zh -2xl -2yl -2zl -2xh -2yh | -2zh 1 1 fh fl 0 0 0] (t)
// Grid: dir(2) x batch(16) x strip(32 of 128 rows) = 1024 blocks x 256 thr
//     -> 4 blocks/CU (LDS 32KB, VGPR<=128), 16 waves/CU.
// Each block scans ALL 4096 target cols -> row-mins FINAL in registers ->
// one atomicAdd per block. No workspace. 2 dispatches (4B memset + kernel).
// K-loop order (R7-proven): barrier -> issue next raw loads -> MFMA+fold ->
// convert+ds_write (vmcnt wait lands after MFMAs covered the latency).

#define BATCH   16
#define NPTS    4096
#define CHUNKC  512
#define NCHUNKS (NPTS / CHUNKC)        // 8
#define NSTRIPS 32                     // 4096 / 128 rows per block

typedef __attribute__((ext_vector_type(8)))  short short8;
typedef __attribute__((ext_vector_type(16))) float float16;

union U4S8 { uint4 u; short8 s; };

__device__ inline unsigned int bfb(float v) {
    __hip_bfloat16 h = __float2bfloat16(v);
    unsigned short u; __builtin_memcpy(&u, &h, 2);
    return (unsigned int)u;
}
__device__ inline float bff(float v) { return __bfloat162float(__float2bfloat16(v)); }

#define ONEB 0x3F80u

__device__ inline void buildA(float x, float y, float z, uint4& w0, uint4& w1) {
    float xhf = bff(x), yhf = bff(y), zhf = bff(z);
    float f = fmaf(x, x, fmaf(y, y, z * z));
    float fhf = bff(f);
    unsigned xh = bfb(xhf), yh = bfb(yhf), zh = bfb(zhf);
    unsigned xl = bfb(x - xhf), yl = bfb(y - yhf), zl = bfb(z - zhf);
    unsigned fh = bfb(fhf), fl = bfb(f - fhf);
    w0 = make_uint4(xh | (yh << 16), zh | (xh << 16),
                    yh | (zh << 16), xl | (yl << 16));
    w1 = make_uint4(zl | (fh << 16), fl | (ONEB << 16), ONEB, 0u);
}

__device__ inline void buildB(float x, float y, float z, uint4& w0, uint4& w1) {
    float xhf = bff(x), yhf = bff(y), zhf = bff(z);
    float f = fmaf(x, x, fmaf(y, y, z * z));
    float fhf = bff(f);
    unsigned a = bfb(-2.0f * xhf), b = bfb(-2.0f * yhf), c = bfb(-2.0f * zhf);
    unsigned d = bfb(-2.0f * (x - xhf)), e = bfb(-2.0f * (y - yhf)),
             g = bfb(-2.0f * (z - zhf));
    unsigned fh = bfb(fhf), fl = bfb(f - fhf);
    w0 = make_uint4(a | (b << 16), c | (d << 16),
                    e | (g << 16), a | (b << 16));
    w1 = make_uint4(c | (ONEB << 16), ONEB | (fh << 16), fl, 0u);
}

__global__ __launch_bounds__(256, 4) void chamfer_kernel(
    const float* __restrict__ src, const float* __restrict__ tgt,
    float* __restrict__ out)
{
    __shared__ uint4 sbuf[2][2][CHUNKC];    // [buf][half][pt] = 32 KB
    __shared__ float wsum[4];

    int blk = blockIdx.x;
    const int strip = blk & (NSTRIPS - 1); blk >>= 5;
    const int b     = blk & 15;            blk >>= 4;
    const int dir   = blk;

    const int t    = threadIdx.x;
    const int lane = t & 63;
    const int w    = t >> 6;
    const int half = lane >> 5;
    const int l5   = lane & 31;

    const float* Araw = (dir ? tgt : src) + (size_t)b * NPTS * 3;  // queries
    const float* Braw = (dir ? src : tgt) + (size_t)b * NPTS * 3;  // targets

    // A fragment: 32 rows per wave (128 per block), built once.
    short8 afr;
    {
        int row = strip * 128 + w * 32 + l5;
        uint4 w0, w1;
        buildA(Araw[3 * row], Araw[3 * row + 1], Araw[3 * row + 2], w0, w1);
        U4S8 tt; tt.u = half ? w1 : w0;
        afr = tt.s;
    }

    // Pipelined B staging: raw loads (regs) early, convert + ds_write late.
    float nx[2][3];
    auto loadRaw = [&](int c) {
#pragma unroll
        for (int k = 0; k < 2; k++) {
            int p = c * CHUNKC + t + k * 256;
            nx[k][0] = Braw[3 * p + 0];
            nx[k][1] = Braw[3 * p + 1];
            nx[k][2] = Braw[3 * p + 2];
        }
    };
    auto convertWrite = [&](int bi) {
#pragma unroll
        for (int k = 0; k < 2; k++) {
            int lp = t + k * 256;
            uint4 w0, w1;
            buildB(nx[k][0], nx[k][1], nx[k][2], w0, w1);
            sbuf[bi][0][lp] = w0;
            sbuf[bi][1][lp] = w1;
        }
    };

    const float16 z16 = {0.f,0.f,0.f,0.f,0.f,0.f,0.f,0.f,
                         0.f,0.f,0.f,0.f,0.f,0.f,0.f,0.f};
    float rm[16];
#pragma unroll
    for (int r = 0; r < 16; r++) rm[r] = 1e30f;

    loadRaw(0);
    convertWrite(0);
    for (int c = 0; c < NCHUNKS; c++) {
        __syncthreads();              // buf[c&1] written; prior-iter reads done
        if (c + 1 < NCHUNKS) loadRaw(c + 1);   // issue, don't wait
        const int bi = c & 1;
#pragma unroll 2
        for (int j2 = 0; j2 < CHUNKC / 64; j2++) {     // 8 steps of 64 cols
            U4S8 t0, t1;
            t0.u = sbuf[bi][half][j2 * 64 + l5];
            t1.u = sbuf[bi][half][j2 * 64 + 32 + l5];
            float16 a0 = __builtin_amdgcn_mfma_f32_32x32x16_bf16(afr, t0.s, z16, 0, 0, 0);
            float16 a1 = __builtin_amdgcn_mfma_f32_32x32x16_bf16(afr, t1.s, z16, 0, 0, 0);
#pragma unroll
            for (int r = 0; r < 16; r++)
                rm[r] = fminf(fminf(a0[r], a1[r]), rm[r]);   // v_min3_f32
        }
        if (c + 1 < NCHUNKS) convertWrite((c + 1) & 1);      // vmcnt hidden
    }

    // Col-fold within half (masks 1..16 over lane&31); each lane then holds
    // 16 final rows for its half; shfl 32 merges the halves' sums.
#pragma unroll
    for (int mask = 1; mask <= 16; mask <<= 1)
#pragma unroll
        for (int r = 0; r < 16; r++)
            rm[r] = fminf(rm[r], __shfl_xor(rm[r], mask, 64));

    float s = 0.0f;
#pragma unroll
    for (int r = 0; r < 16; r++) s += fmaxf(rm[r], 0.0f);
    s += __shfl_xor(s, 32, 64);

    if (lane == 0) wsum[w] = s;
    __syncthreads();
    if (t == 0)
        atomicAdd(out, (wsum[0] + wsum[1] + wsum[2] + wsum[3]) * (1.0f / (float)NPTS));
}

extern "C" void kernel_launch(void* const* d_in, const int* in_sizes, int n_in,
                              void* d_out, int out_size, void* d_ws, size_t ws_size,
                              hipStream_t stream)
{
    const float* src = (const float*)d_in[0];
    const float* tgt = (const float*)d_in[1];
    float* out = (float*)d_out;

    hipMemsetAsync(out, 0, sizeof(float), stream);
    chamfer_kernel<<<2 * BATCH * NSTRIPS, 256, 0, stream>>>(src, tgt, out);
}

// Round 10
// 78.109 us; speedup vs baseline: 1.8259x; 1.0429x over previous
//
#include <hip/hip_runtime.h>
#include <hip/hip_bf16.h>

// Chamfer distance, B=16, N=M=4096, D=3, fp32 — single fused MFMA kernel.
//
// d2(s,t) = |s|^2+|t|^2-2 s.t via ONE K=16 bf16 mfma_f32_32x32x16 per 32x32
// tile with hi/lo bf16 splitting (slot layout verified absmax==0 R4..R9):
//   A: [xh yh zh xh yh zh xl yl | zl fh fl 1 1 0 0 0]           (query s)
//   B: [-2xh -2yh -2zh -2xl -2yl -2zl -2xh -2yh | -2zh 1 1 fh fl 0 0 0] (t)
// Grid: dir(2) x batch(16) x strip(16 of 256 rows) = 512 blocks x 256 thr.
// g=2 row-groups/wave: each 1KB B-fragment LDS read feeds 2 MFMAs (LDS wall
// 5.2 us/CU instead of 10.3). CHUNKC=1024 (64KB LDS dbuf) -> only 4 barriers.
// Inner step: prefetch next B-frags into regs -> issue 4 MFMAs back-to-back
// -> fold 32 v_min3 (max MFMA->readback distance). Row-mins final per block
// -> one atomicAdd. 2 dispatches (4B memset + kernel).

#define BATCH   16
#define NPTS    4096
#define CHUNKC  1024
#define NCHUNKS (NPTS / CHUNKC)        // 4
#define NSTRIPS 16                     // 4096 / 256 rows per block
#define NSTEP   (CHUNKC / 64)          // 16 j2-steps per chunk

typedef __attribute__((ext_vector_type(8)))  short short8;
typedef __attribute__((ext_vector_type(16))) float float16;

union U4S8 { uint4 u; short8 s; };

__device__ inline unsigned int bfb(float v) {
    __hip_bfloat16 h = __float2bfloat16(v);
    unsigned short u; __builtin_memcpy(&u, &h, 2);
    return (unsigned int)u;
}
__device__ inline float bff(float v) { return __bfloat162float(__float2bfloat16(v)); }

#define ONEB 0x3F80u

__device__ inline void buildA(float x, float y, float z, uint4& w0, uint4& w1) {
    float xhf = bff(x), yhf = bff(y), zhf = bff(z);
    float f = fmaf(x, x, fmaf(y, y, z * z));
    float fhf = bff(f);
    unsigned xh = bfb(xhf), yh = bfb(yhf), zh = bfb(zhf);
    unsigned xl = bfb(x - xhf), yl = bfb(y - yhf), zl = bfb(z - zhf);
    unsigned fh = bfb(fhf), fl = bfb(f - fhf);
    w0 = make_uint4(xh | (yh << 16), zh | (xh << 16),
                    yh | (zh << 16), xl | (yl << 16));
    w1 = make_uint4(zl | (fh << 16), fl | (ONEB << 16), ONEB, 0u);
}

__device__ inline void buildB(float x, float y, float z, uint4& w0, uint4& w1) {
    float xhf = bff(x), yhf = bff(y), zhf = bff(z);
    float f = fmaf(x, x, fmaf(y, y, z * z));
    float fhf = bff(f);
    unsigned a = bfb(-2.0f * xhf), b = bfb(-2.0f * yhf), c = bfb(-2.0f * zhf);
    unsigned d = bfb(-2.0f * (x - xhf)), e = bfb(-2.0f * (y - yhf)),
             g = bfb(-2.0f * (z - zhf));
    unsigned fh = bfb(fhf), fl = bfb(f - fhf);
    w0 = make_uint4(a | (b << 16), c | (d << 16),
                    e | (g << 16), a | (b << 16));
    w1 = make_uint4(c | (ONEB << 16), ONEB | (fh << 16), fl, 0u);
}

__global__ __launch_bounds__(256, 2) void chamfer_kernel(
    const float* __restrict__ src, const float* __restrict__ tgt,
    float* __restrict__ out)
{
    __shared__ uint4 sbuf[2][2][CHUNKC];    // [buf][half][pt] = 64 KB
    __shared__ float wsum[4];

    int blk = blockIdx.x;
    const int strip = blk & (NSTRIPS - 1); blk >>= 4;
    const int b     = blk & 15;            blk >>= 4;
    const int dir   = blk;

    const int t    = threadIdx.x;
    const int lane = t & 63;
    const int w    = t >> 6;
    const int half = lane >> 5;
    const int l5   = lane & 31;

    const float* Araw = (dir ? tgt : src) + (size_t)b * NPTS * 3;  // queries
    const float* Braw = (dir ? src : tgt) + (size_t)b * NPTS * 3;  // targets

    // A fragments: 2 row-groups of 32 rows per wave (256 rows per block).
    short8 afr[2];
#pragma unroll
    for (int g = 0; g < 2; g++) {
        int row = strip * 256 + g * 128 + w * 32 + l5;
        uint4 w0, w1;
        buildA(Araw[3 * row], Araw[3 * row + 1], Araw[3 * row + 2], w0, w1);
        U4S8 tt; tt.u = half ? w1 : w0;
        afr[g] = tt.s;
    }

    // Pipelined B staging: raw loads (regs) early, convert + ds_write late.
    float nx[4][3];
    auto loadRaw = [&](int c) {
#pragma unroll
        for (int k = 0; k < 4; k++) {
            int p = c * CHUNKC + t + k * 256;
            nx[k][0] = Braw[3 * p + 0];
            nx[k][1] = Braw[3 * p + 1];
            nx[k][2] = Braw[3 * p + 2];
        }
    };
    auto convertWrite = [&](int bi) {
#pragma unroll
        for (int k = 0; k < 4; k++) {
            int lp = t + k * 256;
            uint4 w0, w1;
            buildB(nx[k][0], nx[k][1], nx[k][2], w0, w1);
            sbuf[bi][0][lp] = w0;
            sbuf[bi][1][lp] = w1;
        }
    };

    const float16 z16 = {0.f,0.f,0.f,0.f,0.f,0.f,0.f,0.f,
                         0.f,0.f,0.f,0.f,0.f,0.f,0.f,0.f};
    float rm[2][16];
#pragma unroll
    for (int g = 0; g < 2; g++)
#pragma unroll
        for (int r = 0; r < 16; r++) rm[g][r] = 1e30f;

    loadRaw(0);
    convertWrite(0);
    for (int c = 0; c < NCHUNKS; c++) {
        __syncthreads();              // buf[c&1] written; prior-iter reads done
        if (c + 1 < NCHUNKS) loadRaw(c + 1);   // issue, don't wait
        const int bi = c & 1;

        // Software-pipelined MFMA loop: prefetch next frags, 4 MFMAs
        // back-to-back, then the 32-min3 fold (spaced from its producers).
        U4S8 c0, c1, n0, n1;
        c0.u = sbuf[bi][half][l5];
        c1.u = sbuf[bi][half][32 + l5];
#pragma unroll 4
        for (int j2 = 0; j2 < NSTEP; j2++) {
            int nj = (j2 + 1) & (NSTEP - 1);           // wrap: harmless re-read
            n0.u = sbuf[bi][half][nj * 64 + l5];
            n1.u = sbuf[bi][half][nj * 64 + 32 + l5];
            float16 a00 = __builtin_amdgcn_mfma_f32_32x32x16_bf16(afr[0], c0.s, z16, 0, 0, 0);
            float16 a01 = __builtin_amdgcn_mfma_f32_32x32x16_bf16(afr[0], c1.s, z16, 0, 0, 0);
            float16 a10 = __builtin_amdgcn_mfma_f32_32x32x16_bf16(afr[1], c0.s, z16, 0, 0, 0);
            float16 a11 = __builtin_amdgcn_mfma_f32_32x32x16_bf16(afr[1], c1.s, z16, 0, 0, 0);
#pragma unroll
            for (int r = 0; r < 16; r++) {
                rm[0][r] = fminf(fminf(a00[r], a01[r]), rm[0][r]);   // v_min3
                rm[1][r] = fminf(fminf(a10[r], a11[r]), rm[1][r]);
            }
            c0 = n0; c1 = n1;
        }
        if (c + 1 < NCHUNKS) convertWrite((c + 1) & 1);      // vmcnt hidden
    }

    // Col-fold within half (masks 1..16 over lane&31); each lane then holds
    // 2x16 final rows for its half; shfl 32 merges the halves' sums.
#pragma unroll
    for (int mask = 1; mask <= 16; mask <<= 1)
#pragma unroll
        for (int g = 0; g < 2; g++)
#pragma unroll
            for (int r = 0; r < 16; r++)
                rm[g][r] = fminf(rm[g][r], __shfl_xor(rm[g][r], mask, 64));

    float s = 0.0f;
#pragma unroll
    for (int g = 0; g < 2; g++)
#pragma unroll
        for (int r = 0; r < 16; r++) s += fmaxf(rm[g][r], 0.0f);
    s += __shfl_xor(s, 32, 64);

    if (lane == 0) wsum[w] = s;
    __syncthreads();
    if (t == 0)
        atomicAdd(out, (wsum[0] + wsum[1] + wsum[2] + wsum[3]) * (1.0f / (float)NPTS));
}

extern "C" void kernel_launch(void* const* d_in, const int* in_sizes, int n_in,
                              void* d_out, int out_size, void* d_ws, size_t ws_size,
                              hipStream_t stream)
{
    const float* src = (const float*)d_in[0];
    const float* tgt = (const float*)d_in[1];
    float* out = (float*)d_out;

    hipMemsetAsync(out, 0, sizeof(float), stream);
    chamfer_kernel<<<2 * BATCH * NSTRIPS, 256, 0, stream>>>(src, tgt, out);
}